// Round 1
// baseline (79.074 us; speedup 1.0000x reference)
//
#include <hip/hip_runtime.h>

// CapsuleConv2d: x (4,32,56,56) f32, weight (P_out=4,P_in=4,K=9,L_in=8,L_out=16) f32
// out (4,64,56,56) f32. 3x3 conv s1 p1, 3 routing iterations.
//
// Lane = dq(bits 0-1: d-quarter) x wl(bits 2-3: 4 w-sites) x p(bits 4-5: plane).
// dq in the QUAD bits so the d-reduction (squash norm, logit updates) is two DPP
// quad_perm adds (pure VALU, no DS pipe). T=2: each wave owns two h-adjacent rows
// of 4 sites; one ds_read_b128 weight broadcast feeds 8 sites. M[9][4][2] = 72 VGPRs.
//
// R8 (this round): block re-tiled to 4 rows x 8 cols (2x2 waves); x halo tile
// (6 rows x 10 cols x 32 ch = 7.9 KB) staged coalesced into LDS once. Inner loop
// is now pure LDS with compile-time immediate offsets (12 ds_read_b32 + 9
// ds_read_b128 + 72 fmac per l) -- kills the 8 serial global-load round trips
// that dominated the ~38 us kernel time (bench 78 us = ~40 us harness ws-fill
// + kernel). x LDS layout is ch-fastest, (r*10+c) stride 33: a read's 16 unique
// lane addrs hit 16 distinct banks (p->+8, wl->+1, dq broadcast) -- conflict-free.
//
// REGISTER LESSONS (R3-R6): any occupancy attribute caused forced spills
// (84/64/128-cap -> up to 887 MB scratch). NO attributes + unroll(disable) on the
// l-loop keeps live set ~120 and eliminated all scratch traffic (R6).

#define HW 56
#define HW2 3136
#define WSTRIDE 1168
#define XSTR 33            // (r*10+c) stride in floats, +1 pad for bank spread
#define XN (60 * XSTR)     // 1980 floats = 7920 B

// sum over the 4 lanes of a quad: x + quad_perm[1,0,3,2] then + quad_perm[2,3,0,1]
__device__ __forceinline__ float quad_add1(float x) {
    int y = __builtin_amdgcn_update_dpp(0, __float_as_int(x), 0xB1, 0xF, 0xF, true);
    return x + __int_as_float(y);
}
__device__ __forceinline__ float quad_add2(float x) {
    int y = __builtin_amdgcn_update_dpp(0, __float_as_int(x), 0x4E, 0xF, 0xF, true);
    return x + __int_as_float(y);
}
__device__ __forceinline__ float quad_reduce(float x) {
    return quad_add2(quad_add1(x));
}

__global__ void caps_routing_kernel(
    const float* __restrict__ x, const float* __restrict__ wgt,
    float* __restrict__ out)
{
    __shared__ float lds_w[4 * WSTRIDE];   // 18688 B
    __shared__ float lds_x[XN];            //  7920 B  (total 26608 B/block)

    const int tid = threadIdx.x;
    const int bx  = blockIdx.x;          // n*4 + o
    const int n = bx >> 2, o = bx & 3;

    // block tile: 4 output rows x 8 output cols
    const int by = blockIdx.y;           // 98 = 14 h-blocks x 7 w-blocks
    const int hb = by / 7;
    const int wb = by - hb * 7;
    const int h0 = hb * 4;
    const int w0 = wb * 8;

    // ---- stage weight slice wgt[o][p][k][l][d] (4608 floats) into LDS ----
    {
        const float4* wsrc = (const float4*)(wgt + o * 4608);
        for (int i = tid; i < 1152; i += 256) {
            const int pp  = i / 288;          // 288 float4 per p-plane
            const int rem = i - pp * 288;
            *(float4*)&lds_w[pp * WSTRIDE + rem * 4] = wsrc[i];
        }
    }
    // ---- stage x halo tile: 32 ch x 6 rows x 10 cols, coalesced, bounds once ----
    {
        const float* xn = x + n * 32 * HW2;
        for (int idx = tid; idx < 1920; idx += 256) {
            const int ch  = idx / 60;         // p*8 + l
            const int rem = idx - ch * 60;    // r*10 + c
            const int r   = rem / 10;
            const int c   = rem - r * 10;
            const int gr  = h0 - 1 + r;
            const int gc  = w0 - 1 + c;
            float v = 0.f;
            if ((unsigned)gr < (unsigned)HW && (unsigned)gc < (unsigned)HW)
                v = xn[ch * HW2 + gr * HW + gc];
            lds_x[rem * XSTR + ch] = v;
        }
    }
    __syncthreads();

    const int dq = tid & 3;              // quad bits -> DPP-reducible
    const int wl = (tid >> 2) & 3;
    const int p  = (tid >> 4) & 3;
    const int wi = tid >> 6;             // wave: hh = wi>>1 (2 row-pairs), ww = wi&1
    const int hh = wi >> 1, ww = wi & 1;

    // M[k][j][ti]: priors for the lane's 4 d's at sites (h0+hh*2+ti, w0+ww*4+wl)
    float M[9][4][2];
    #pragma unroll
    for (int k = 0; k < 9; ++k)
        #pragma unroll
        for (int j = 0; j < 4; ++j) { M[k][j][0] = 0.f; M[k][j][1] = 0.f; }

    // all inner-loop LDS offsets are compile-time immediates off these bases
    const float* xb  = &lds_x[((hh * 2) * 10 + ww * 4 + wl) * XSTR + p * 8];
    const float* wbp = &lds_w[p * WSTRIDE + dq * 4];

    #pragma clang loop unroll(disable)
    for (int l = 0; l < 8; ++l) {
        const float* xl  = xb + l;
        const float* wlp = wbp + l * 16;
        // 4 rows (h-1 .. h+2) x 3 cols, shared between the two tiles
        float xv[4][3];
        #pragma unroll
        for (int rr = 0; rr < 4; ++rr)
            #pragma unroll
            for (int c = 0; c < 3; ++c)
                xv[rr][c] = xl[(rr * 10 + c) * XSTR];
        #pragma unroll
        for (int rr = 0; rr < 3; ++rr) {
            #pragma unroll
            for (int kc = 0; kc < 3; ++kc) {
                const int k = rr * 3 + kc;
                const float4 wa = *(const float4*)(wlp + k * 128);
                const float xs0 = xv[rr][kc];       // tile 0 (row h0+hh*2)
                const float xs1 = xv[rr + 1][kc];   // tile 1 (row h0+hh*2+1)
                M[k][0][0] += xs0 * wa.x; M[k][1][0] += xs0 * wa.y;
                M[k][2][0] += xs0 * wa.z; M[k][3][0] += xs0 * wa.w;
                M[k][0][1] += xs1 * wa.x; M[k][1][1] += xs1 * wa.y;
                M[k][2][1] += xs1 * wa.z; M[k][3][1] += xs1 * wa.w;
            }
        }
    }

    // ---- dynamic routing (3 iters; iter 0 uniform probs = 1/9), per tile ----
    #pragma unroll
    for (int ti = 0; ti < 2; ++ti) {
        float v[4], b[9];
        {
            float s[4];
            #pragma unroll
            for (int j = 0; j < 4; ++j) {
                float a = M[0][j][ti];
                #pragma unroll
                for (int k = 1; k < 9; ++k) a += M[k][j][ti];
                s[j] = a * (1.f / 9.f);
            }
            float sq = s[0]*s[0] + s[1]*s[1] + s[2]*s[2] + s[3]*s[3];
            sq = quad_reduce(sq);
            const float scale = sq * __builtin_amdgcn_rsqf(sq) * __builtin_amdgcn_rcpf(1.f + sq);
            #pragma unroll
            for (int j = 0; j < 4; ++j) v[j] = s[j] * scale;
            #pragma unroll
            for (int k = 0; k < 9; ++k) {
                float u = M[k][0][ti]*v[0] + M[k][1][ti]*v[1]
                        + M[k][2][ti]*v[2] + M[k][3][ti]*v[3];
                b[k] = quad_reduce(u);
            }
        }

        #pragma unroll
        for (int it = 1; it < 3; ++it) {
            float mx = b[0];
            #pragma unroll
            for (int k = 1; k < 9; ++k) mx = fmaxf(mx, b[k]);
            float e[9]; float se = 0.f;
            #pragma unroll
            for (int k = 0; k < 9; ++k) { e[k] = __expf(b[k] - mx); se += e[k]; }
            const float inv = __builtin_amdgcn_rcpf(se);
            float s[4];
            #pragma unroll
            for (int j = 0; j < 4; ++j) {
                float a = 0.f;
                #pragma unroll
                for (int k = 0; k < 9; ++k) a += e[k] * M[k][j][ti];
                s[j] = a * inv;
            }
            float sq = s[0]*s[0] + s[1]*s[1] + s[2]*s[2] + s[3]*s[3];
            sq = quad_reduce(sq);
            const float scale = sq * __builtin_amdgcn_rsqf(sq) * __builtin_amdgcn_rcpf(1.f + sq);
            #pragma unroll
            for (int j = 0; j < 4; ++j) v[j] = s[j] * scale;
            if (it == 1) {
                #pragma unroll
                for (int k = 0; k < 9; ++k) {
                    float u = M[k][0][ti]*v[0] + M[k][1][ti]*v[1]
                            + M[k][2][ti]*v[2] + M[k][3][ti]*v[3];
                    b[k] += quad_reduce(u);
                }
            }
        }

        // ---- sum over p (lane bits 4,5), store row h0+hh*2+ti ----
        #pragma unroll
        for (int j = 0; j < 4; ++j) {
            v[j] += __shfl_xor(v[j], 16, 64);
            v[j] += __shfl_xor(v[j], 32, 64);
        }
        if (p == 0) {
            float* op = out + ((n * 64 + o * 16 + dq * 4) * HW + (h0 + hh * 2 + ti)) * HW
                      + w0 + ww * 4 + wl;
            #pragma unroll
            for (int j = 0; j < 4; ++j) op[j * HW2] = v[j];
        }
    }
}

extern "C" void kernel_launch(void* const* d_in, const int* in_sizes, int n_in,
                              void* d_out, int out_size, void* d_ws, size_t ws_size,
                              hipStream_t stream) {
    const float* x   = (const float*)d_in[0];
    const float* wgt = (const float*)d_in[1];
    float* out = (float*)d_out;

    // grid: x = n*4+o (16), y = 98 blocks = 14 h-blocks x 7 w-blocks
    caps_routing_kernel<<<dim3(16, 98), dim3(256), 0, stream>>>(x, wgt, out);
}